// Round 3
// baseline (2248.240 us; speedup 1.0000x reference)
//
#include <hip/hip_runtime.h>
#include <hip/hip_bf16.h>

#define B_ 4
#define H_ 240
#define W_ 1216
#define HW_ (H_*W_)        /* 291840 */
#define N1_ (B_*HW_)       /* 1167360 */
#define PT_ 18

// ---------- dtype-agnostic load/store (runtime bf16-vs-fp32 probe) ----------
// aff_scale_const == 4.0: bf16 -> halfword 0x4080 at offset 0; fp32 -> 0x0000.
__device__ __forceinline__ bool probe_bf16(const void* scale_ptr) {
    return ((const unsigned short*)scale_ptr)[0] == 0x4080;
}

__device__ __forceinline__ float ldin(const void* p, int i, bool bf) {
    if (bf) {
        unsigned int u = (unsigned int)((const unsigned short*)p)[i];
        return __uint_as_float(u << 16);
    }
    return ((const float*)p)[i];
}

__device__ __forceinline__ void stout(void* p, int i, bool bf, float v) {
    if (bf) ((__hip_bfloat16*)p)[i] = __float2bfloat16(v);
    else    ((float*)p)[i] = v;
}

// ------- kernel 1: stage conv weights to fp32 scratch, tap-major layout -----
// src layout (24,8,3,3): i = co*72 + ci*9 + t  ->  dst (t*8+ci)*24 + co
__global__ __launch_bounds__(256) void k_prep_w(const void* __restrict__ w_oa,
                                                const void* __restrict__ b_oa,
                                                const void* __restrict__ scale,
                                                float* __restrict__ wc) {
    bool bf = probe_bf16(scale);
    int i = blockIdx.x * 256 + threadIdx.x;
    if (i < 1728) {
        int co = i / 72;
        int rem = i - co * 72;
        int ci = rem / 9;
        int t = rem - ci * 9;
        wc[(t * 8 + ci) * 24 + co] = ldin(w_oa, i, bf);
    }
    if (i < 24) wc[1728 + i] = ldin(b_oa, i, bf);
}

// ---------------- kernel 2: feat0 = mask ? feat_fix : feat_init -------------
__global__ __launch_bounds__(256) void k_init(const void* __restrict__ finit,
                                              const void* __restrict__ ffix,
                                              const void* __restrict__ scale,
                                              float* __restrict__ featA) {
    bool bf = probe_bf16(scale);
    int p = blockIdx.x * 256 + threadIdx.x;
    if (p >= N1_) return;
    float fx = ldin(ffix, p, bf);
    featA[p] = (fx > 0.0f) ? fx : ldin(finit, p, bf);
}

// --------- kernel 3: 3x3 conv (8->24) + offsets/affinity epilogue -----------
// Tap-major accumulation: live set ~35 VGPRs, no g[72] array, no spill.
// Offset pairing per reference: off[:, t, 0] = oa[2t] (y), off[:, t, 1] = oa[2t+1] (x)
__global__ __launch_bounds__(256) void k_conv(const void* __restrict__ guid,
                                              const void* __restrict__ conf,
                                              const void* __restrict__ ffix,
                                              const void* __restrict__ scale,
                                              const float* __restrict__ wc,
                                              void* __restrict__ d_out,
                                              float4* __restrict__ ws_pack,
                                              int mode2) {
    bool bf = probe_bf16(scale);
    int p = blockIdx.x * 256 + threadIdx.x;
    if (p >= N1_) return;
    int b = p / HW_;
    int r = p - b * HW_;
    int h = r / W_;
    int w = r - h * W_;

    float oa[24];
    #pragma unroll
    for (int co = 0; co < 24; ++co) oa[co] = wc[1728 + co];

    const int gbase = b * 8 * HW_;
    #pragma unroll
    for (int t = 0; t < 9; ++t) {
        int hh = h + t / 3 - 1;
        int ww = w + t % 3 - 1;
        bool v = (hh >= 0) && (hh < H_) && (ww >= 0) && (ww < W_);
        int idx0 = hh * W_ + ww;
        float gv[8];
        #pragma unroll
        for (int ci = 0; ci < 8; ++ci)
            gv[ci] = v ? ldin(guid, gbase + ci * HW_ + idx0, bf) : 0.0f;
        #pragma unroll
        for (int ci = 0; ci < 8; ++ci) {
            float g = gv[ci];
            const float* wrow = wc + (t * 8 + ci) * 24;
            #pragma unroll
            for (int co = 0; co < 24; ++co)
                oa[co] = fmaf(g, wrow[co], oa[co]);
        }
    }

    float scl = ldin(scale, 0, bf);
    float inv = 1.0f / (scl + 1e-8f);

    // affinity: tanh/scale, bilinear confidence at (h+oy, w+ox), normalize
    float aft[8];
    int cbase = b * HW_;
    #pragma unroll
    for (int t = 0; t < 8; ++t) {
        float a = tanhf(oa[16 + t]) * inv;
        float y = (float)h + oa[2 * t];        // y-offset = oa[2t]
        float x = (float)w + oa[2 * t + 1];    // x-offset = oa[2t+1]
        float y0f = floorf(y), x0f = floorf(x);
        int y0 = (int)y0f, x0 = (int)x0f;
        float wy = y - y0f, wx = x - x0f;
        int y0c = min(max(y0, 0), H_ - 1), y1c = min(max(y0 + 1, 0), H_ - 1);
        int x0c = min(max(x0, 0), W_ - 1), x1c = min(max(x0 + 1, 0), W_ - 1);
        bool vy0 = (y0 >= 0) && (y0 < H_), vy1 = (y0 >= -1) && (y0 < H_ - 1);
        bool vx0 = (x0 >= 0) && (x0 < W_), vx1 = (x0 >= -1) && (x0 < W_ - 1);
        float w00 = (1.0f - wy) * (1.0f - wx); w00 = (vy0 && vx0) ? w00 : 0.0f;
        float w01 = (1.0f - wy) * wx;          w01 = (vy0 && vx1) ? w01 : 0.0f;
        float w10 = wy * (1.0f - wx);          w10 = (vy1 && vx0) ? w10 : 0.0f;
        float w11 = wy * wx;                   w11 = (vy1 && vx1) ? w11 : 0.0f;
        float f00 = ldin(conf, cbase + y0c * W_ + x0c, bf);
        float f01 = ldin(conf, cbase + y0c * W_ + x1c, bf);
        float f10 = ldin(conf, cbase + y1c * W_ + x0c, bf);
        float f11 = ldin(conf, cbase + y1c * W_ + x1c, bf);
        float cv = w00 * f00 + w01 * f01 + w10 * f10 + w11 * f11;
        aft[t] = a * cv;
    }
    float s = 1e-4f;
    #pragma unroll
    for (int t = 0; t < 8; ++t) s += fabsf(aft[t]);
    s = fmaxf(s, 1.0f);
    float rs = 1.0f / s;
    float suma = 0.0f;
    #pragma unroll
    for (int t = 0; t < 8; ++t) { aft[t] *= rs; suma += aft[t]; }
    float aref = 1.0f - suma;

    // outputs: off (18 planes, center pair zero) and aff9 (9 planes)
    #pragma unroll
    for (int t = 0; t < 8; ++t) {
        int n9 = t + (t >= 4 ? 1 : 0);
        stout(d_out, N1_ + (b * 18 + 2 * n9)     * HW_ + r, bf, oa[2 * t]);
        stout(d_out, N1_ + (b * 18 + 2 * n9 + 1) * HW_ + r, bf, oa[2 * t + 1]);
        stout(d_out, 19 * N1_ + (b * 9 + n9) * HW_ + r, bf, aft[t]);
    }
    stout(d_out, N1_ + (b * 18 + 8) * HW_ + r, bf, 0.0f);
    stout(d_out, N1_ + (b * 18 + 9) * HW_ + r, bf, 0.0f);
    stout(d_out, 19 * N1_ + (b * 9 + 4) * HW_ + r, bf, aref);

    if (mode2) {
        float fx = ldin(ffix, p, bf);
        // 7 float4 groups per pixel, plane-group interleaved for coalescing
        ws_pack[0 * N1_ + p] = make_float4(oa[0], oa[2], oa[4], oa[6]);    // oy0..3
        ws_pack[1 * N1_ + p] = make_float4(oa[8], oa[10], oa[12], oa[14]); // oy4..7
        ws_pack[2 * N1_ + p] = make_float4(oa[1], oa[3], oa[5], oa[7]);    // ox0..3
        ws_pack[3 * N1_ + p] = make_float4(oa[9], oa[11], oa[13], oa[15]); // ox4..7
        ws_pack[4 * N1_ + p] = make_float4(aft[0], aft[1], aft[2], aft[3]);
        ws_pack[5 * N1_ + p] = make_float4(aft[4], aft[5], aft[6], aft[7]);
        ws_pack[6 * N1_ + p] = make_float4(aref, fx, 0.0f, 0.0f);
    }
}

// ---------------- kernel 4: one propagation step ----------------------------
__global__ __launch_bounds__(256) void k_prop(const float* __restrict__ src,
                                              float* __restrict__ dst,
                                              const float4* __restrict__ ws_pack,
                                              const void* __restrict__ d_out_all,
                                              const void* __restrict__ ffix_in,
                                              const void* __restrict__ scale,
                                              void* __restrict__ d_out_feat,
                                              int last, int mode2) {
    int p = blockIdx.x * 256 + threadIdx.x;
    if (p >= N1_) return;
    int b = p / HW_;
    int r = p - b * HW_;
    int h = r / W_;
    int w = r - h * W_;
    const float* sp = src + b * HW_;

    float oy[8], ox[8], af[9], fx;
    if (mode2) {
        float4 g0 = ws_pack[0 * N1_ + p];
        float4 g1 = ws_pack[1 * N1_ + p];
        float4 g2 = ws_pack[2 * N1_ + p];
        float4 g3 = ws_pack[3 * N1_ + p];
        float4 g4 = ws_pack[4 * N1_ + p];
        float4 g5 = ws_pack[5 * N1_ + p];
        float4 g6 = ws_pack[6 * N1_ + p];
        oy[0]=g0.x; oy[1]=g0.y; oy[2]=g0.z; oy[3]=g0.w;
        oy[4]=g1.x; oy[5]=g1.y; oy[6]=g1.z; oy[7]=g1.w;
        ox[0]=g2.x; ox[1]=g2.y; ox[2]=g2.z; ox[3]=g2.w;
        ox[4]=g3.x; ox[5]=g3.y; ox[6]=g3.z; ox[7]=g3.w;
        af[0]=g4.x; af[1]=g4.y; af[2]=g4.z; af[3]=g4.w;
        af[5]=g5.x; af[6]=g5.y; af[7]=g5.z; af[8]=g5.w;
        af[4]=g6.x; fx=g6.y;
    } else {
        bool bf = probe_bf16(scale);
        #pragma unroll
        for (int t = 0; t < 8; ++t) {
            int n9 = t + (t >= 4 ? 1 : 0);
            oy[t] = ldin(d_out_all, N1_ + (b * 18 + 2 * n9)     * HW_ + r, bf);
            ox[t] = ldin(d_out_all, N1_ + (b * 18 + 2 * n9 + 1) * HW_ + r, bf);
        }
        #pragma unroll
        for (int n = 0; n < 9; ++n)
            af[n] = ldin(d_out_all, 19 * N1_ + (b * 9 + n) * HW_ + r, bf);
        fx = ldin(ffix_in, p, bf);
    }

    // center tap: zero offset -> exact grid sample
    float acc = af[4] * sp[r];

    #pragma unroll
    for (int t = 0; t < 8; ++t) {
        int n9 = t + (t >= 4 ? 1 : 0);
        float y = (float)(h + n9 / 3 - 1) + oy[t];
        float x = (float)(w + n9 % 3 - 1) + ox[t];
        float y0f = floorf(y), x0f = floorf(x);
        int y0 = (int)y0f, x0 = (int)x0f;
        float wy = y - y0f, wx = x - x0f;
        int y0c = min(max(y0, 0), H_ - 1), y1c = min(max(y0 + 1, 0), H_ - 1);
        int x0c = min(max(x0, 0), W_ - 1), x1c = min(max(x0 + 1, 0), W_ - 1);
        bool vy0 = (y0 >= 0) && (y0 < H_), vy1 = (y0 >= -1) && (y0 < H_ - 1);
        bool vx0 = (x0 >= 0) && (x0 < W_), vx1 = (x0 >= -1) && (x0 < W_ - 1);
        float w00 = (1.0f - wy) * (1.0f - wx); w00 = (vy0 && vx0) ? w00 : 0.0f;
        float w01 = (1.0f - wy) * wx;          w01 = (vy0 && vx1) ? w01 : 0.0f;
        float w10 = wy * (1.0f - wx);          w10 = (vy1 && vx0) ? w10 : 0.0f;
        float w11 = wy * wx;                   w11 = (vy1 && vx1) ? w11 : 0.0f;
        float f00 = sp[y0c * W_ + x0c];
        float f01 = sp[y0c * W_ + x1c];
        float f10 = sp[y1c * W_ + x0c];
        float f11 = sp[y1c * W_ + x1c];
        float v = w00 * f00 + w01 * f01 + w10 * f10 + w11 * f11;
        acc = fmaf(af[n9], v, acc);
    }

    if (last) {
        stout(d_out_feat, p, probe_bf16(scale), acc);
    } else {
        dst[p] = (fx > 0.0f) ? fx : acc;   // fold next step's mask-replace
    }
}

extern "C" void kernel_launch(void* const* d_in, const int* in_sizes, int n_in,
                              void* d_out, int out_size, void* d_ws, size_t ws_size,
                              hipStream_t stream) {
    const void* feat_init  = d_in[0];
    const void* guidance   = d_in[1];
    const void* confidence = d_in[2];
    const void* feat_fix   = d_in[3];
    const void* w_oa       = d_in[4];
    const void* b_oa       = d_in[5];
    const void* scale      = d_in[6];

    float* wsf     = (float*)d_ws;
    float* featA   = wsf;
    float* featB   = wsf + N1_;
    float* wc      = wsf + 2 * (size_t)N1_;
    float4* ws_pack = (float4*)(wsf + 2 * (size_t)N1_ + 2048);

    size_t need2 = ((size_t)30 * N1_ + 2048) * sizeof(float);
    int mode2 = (ws_size >= need2) ? 1 : 0;

    int grid = (N1_ + 255) / 256;
    hipLaunchKernelGGL(k_prep_w, dim3(7), dim3(256), 0, stream, w_oa, b_oa, scale, wc);
    hipLaunchKernelGGL(k_init, dim3(grid), dim3(256), 0, stream,
                       feat_init, feat_fix, scale, featA);
    hipLaunchKernelGGL(k_conv, dim3(grid), dim3(256), 0, stream,
                       guidance, confidence, feat_fix, scale, wc, d_out, ws_pack, mode2);

    float* a = featA;
    float* bbuf = featB;
    for (int it = 0; it < PT_; ++it) {
        int last = (it == PT_ - 1) ? 1 : 0;
        hipLaunchKernelGGL(k_prop, dim3(grid), dim3(256), 0, stream,
                           a, bbuf, ws_pack, d_out, feat_fix, scale,
                           d_out, last, mode2);
        float* t = a; a = bbuf; bbuf = t;
    }
}